// Round 9
// baseline (576.312 us; speedup 1.0000x reference)
//
#include <hip/hip_runtime.h>

typedef unsigned short u16;
typedef unsigned int u32;

#define Bb 2
#define Lc 2048
#define Dc 2048
#define Hc 16
#define DhC 128

typedef __bf16 bf16x8 __attribute__((ext_vector_type(8)));
typedef float f32x4 __attribute__((ext_vector_type(4)));
typedef float f32x16 __attribute__((ext_vector_type(16)));

__device__ __forceinline__ u16 f2b(float f) {
  u32 u = __float_as_uint(f);
  u32 r = (u + 0x7fffu + ((u >> 16) & 1u)) >> 16;
  return (u16)r;
}
__device__ __forceinline__ float b2f(u16 u) {
  return __uint_as_float(((u32)u) << 16);
}

// pack 2 f32 -> 1 u32 of 2 bf16 (lo in low half) -- T12 recipe, no builtin
__device__ __forceinline__ u32 cvtpk(float lo, float hi) {
  u32 r;
  asm("v_cvt_pk_bf16_f32 %0, %1, %2" : "=v"(r) : "v"(lo), "v"(hi));
  return r;
}

// async global->LDS DMA, 16B/lane; LDS dest = wave-uniform base + lane*16
__device__ __forceinline__ void gll16(const void* g, void* l) {
  __builtin_amdgcn_global_load_lds(
      (const __attribute__((address_space(1))) u32*)g,
      (__attribute__((address_space(3))) u32*)l, 16, 0, 0);
}

// ---------------------------------------------------------------------------
// Dtype sniffer + x canonicalize (kept; inputs verified bf16-compatible r4).
// ---------------------------------------------------------------------------
__global__ __launch_bounds__(256) void sniff_dtype(const u16* __restrict__ x,
                                                   int* __restrict__ flag) {
  __shared__ int bad;
  if (threadIdx.x == 0) bad = 0;
  __syncthreads();
  int local = 0;
  for (int i = threadIdx.x; i < 65536; i += 256) {
    float v = fabsf(b2f(x[i]));
    if (!(v < 1000.f)) local = 1;
  }
  if (local) atomicOr(&bad, 1);
  __syncthreads();
  if (threadIdx.x == 0) *flag = bad;
}

__global__ __launch_bounds__(256) void conv_x(const void* __restrict__ in,
                                              u16* __restrict__ out,
                                              const int* __restrict__ flag) {
  const int f32 = *flag;
  const int i0 = (blockIdx.x * 256 + threadIdx.x) * 4;
  if (f32) {
    const float* p = (const float*)in;
#pragma unroll
    for (int j = 0; j < 4; j++) out[i0 + j] = f2b(p[i0 + j]);
  } else {
    const u16* p = (const u16*)in;
#pragma unroll
    for (int j = 0; j < 4; j++) out[i0 + j] = p[i0 + j];
  }
}

// ---------------------------------------------------------------------------
// 2048x2048 transpose with dtype conversion (weights -> bf16 W^T).
// transpose3_conv: z-indexed fused variant for the 3 QKV weights.
// ---------------------------------------------------------------------------
__device__ __forceinline__ void tconv_body(const void* in, u16* out, int f32) {
  __shared__ __align__(16) u16 tile[64][65];
  const int r0 = blockIdx.y * 64, c0 = blockIdx.x * 64;
  const int tc = threadIdx.x & 63, tr4 = threadIdx.x >> 6;
#pragma unroll
  for (int p = 0; p < 16; p++) {
    int r = tr4 + p * 4;
    size_t idx = (size_t)(r0 + r) * 2048 + c0 + tc;
    tile[r][tc] = f32 ? f2b(((const float*)in)[idx]) : ((const u16*)in)[idx];
  }
  __syncthreads();
#pragma unroll
  for (int p = 0; p < 16; p++) {
    int rr = tr4 + p * 4;
    out[(size_t)(c0 + rr) * 2048 + r0 + tc] = tile[tc][rr];
  }
}

__global__ __launch_bounds__(256) void transpose2d_conv(const void* __restrict__ in,
                                                        u16* __restrict__ out,
                                                        const int* __restrict__ flag) {
  tconv_body(in, out, *flag);
}

__global__ __launch_bounds__(256) void transpose3_conv(const void* __restrict__ W0,
                                                       const void* __restrict__ W1,
                                                       const void* __restrict__ W2,
                                                       u16* __restrict__ out,
                                                       const int* __restrict__ flag) {
  const int z = blockIdx.z;
  const void* in = (z == 0) ? W0 : (z == 1) ? W1 : W2;
  tconv_body(in, out + (size_t)z * 2048 * 2048, *flag);
}

// ---------------------------------------------------------------------------
// GEMM r14 "gemmk" (resubmit -- r8 bench was an infra failure, no data):
// BK=64 -> 32 K-iterations (r9-r13 evidence: per-iter wall cost is ~fixed
// regardless of per-iter MFMA; halving iters halves the fixed cost -- the
// Wo gemm at 64 light iters was ~250us for 34 GF).
//  - BM=128 x BN=256, 512 thr (8 waves 2M x 4N), per-wave 64x64 = acc[4][4].
//  - 2-slot ring, counted vmcnt at TOP of iter: iter t stages tile t+1 into
//    slot^1 (6 gll16/thread), then vmcnt(6) confirms tile t (leaves t+1's 6
//    in flight), s_barrier, compute, s_barrier. In-flight DMA always targets
//    the buffer nobody reads this iter -> race-free. vmcnt(0) only at t=31.
//  - fragment-order LDS at BK=64: subtile = 16 rows x 64 cols (2 KB); lane
//    l's frag for k-step ks at subtile*2048B + ks*1024B + l*16B. Stage src =
//    per-lane global (row l&15, chunk l>>4, col-base ks*32); dest linear.
//    Reads are wave-linear contiguous 1KB -> 0 bank conflicts (verified r10+).
//  - LDS 2*(16+32) = 96 KB -> 1 blk/CU. Grids exact CU rounds: QKV 768
//    (3 rounds), Wo 256 (1 round). XCD-chunked swizzle.
//  - FUSEV epilogue (QKV): V cols written directly transposed (B,H,Dh,L).
// ---------------------------------------------------------------------------
template <typename OutT, bool FUSEV>
__device__ __forceinline__ void gemmk_core(const u16* __restrict__ A,
                                           const u16* __restrict__ Bt,
                                           OutT* __restrict__ C,
                                           u16* __restrict__ Vt,
                                           int nwg, size_t bufStride) {
  constexpr int K = 2048;
  __shared__ __align__(16) u16 Asl[2][128 * 64];
  __shared__ __align__(16) u16 Bsl[2][256 * 64];

  const int tid = threadIdx.x;
  const int lane = tid & 63, w = tid >> 6;  // 8 waves
  const int quad = lane >> 4, l15 = lane & 15;
  const int wm = w >> 2, wn = w & 3;  // 2M x 4N, per-wave 64x64

  // XCD-chunked bijective swizzle (nwg: 768, 256 -- both %8==0)
  const int q8 = nwg >> 3;
  const int id = (int)blockIdx.x;
  const int swz = (id & 7) * q8 + (id >> 3);
  const int m0 = (swz & 31) * 128;   // 32 M-tiles (M=4096)
  const int n0 = (swz >> 5) * 256;

  // fragment-order staging sources (per-lane: row l&15, chunk l>>4)
  const u16* aS = A + (size_t)(m0 + w * 16 + l15) * K + (lane >> 4) * 8;
  const u16* bS = Bt + (size_t)(n0 + (2 * w) * 16 + l15) * K + (lane >> 4) * 8;

  const f32x4 fz = {0.f, 0.f, 0.f, 0.f};
  f32x4 acc[4][4];
#pragma unroll
  for (int i = 0; i < 4; i++)
#pragma unroll
    for (int j = 0; j < 4; j++) acc[i][j] = fz;

  // stage tile t into slot sl: A subtile w (2 gll16), B subtiles 2w,2w+1 (4)
  auto stage = [&](int t, int sl) {
    const int kk = t * 64;
    gll16(aS + kk, &Asl[sl][w * 1024]);
    gll16(aS + kk + 32, &Asl[sl][w * 1024 + 512]);
    gll16(bS + kk, &Bsl[sl][(2 * w) * 1024]);
    gll16(bS + kk + 32, &Bsl[sl][(2 * w) * 1024 + 512]);
    gll16(bS + (size_t)16 * K + kk, &Bsl[sl][(2 * w + 1) * 1024]);
    gll16(bS + (size_t)16 * K + kk + 32, &Bsl[sl][(2 * w + 1) * 1024 + 512]);
  };

  auto compute = [&](int sl) {
    bf16x8 afr[4][2], bfr[4][2];
#pragma unroll
    for (int mt = 0; mt < 4; mt++)
#pragma unroll
      for (int ks = 0; ks < 2; ks++)
        afr[mt][ks] = *(const bf16x8*)(
            &Asl[sl][(wm * 4 + mt) * 1024 + ks * 512 + lane * 8]);
#pragma unroll
    for (int nt = 0; nt < 4; nt++)
#pragma unroll
      for (int ks = 0; ks < 2; ks++)
        bfr[nt][ks] = *(const bf16x8*)(
            &Bsl[sl][(wn * 4 + nt) * 1024 + ks * 512 + lane * 8]);
    asm volatile("s_waitcnt lgkmcnt(0)" ::: "memory");
    __builtin_amdgcn_sched_barrier(0);
    __builtin_amdgcn_s_setprio(1);
#pragma unroll
    for (int ks = 0; ks < 2; ks++)
#pragma unroll
      for (int mt = 0; mt < 4; mt++)
#pragma unroll
        for (int nt = 0; nt < 4; nt++)
          acc[mt][nt] = __builtin_amdgcn_mfma_f32_16x16x32_bf16(
              afr[mt][ks], bfr[nt][ks], acc[mt][nt], 0, 0, 0);
    __builtin_amdgcn_s_setprio(0);
  };

  // prologue: stage tile 0 into slot 0
  stage(0, 0);

  // main: 32 K-tiles; unroll x2 for compile-time slots; peel t=30,31
#pragma unroll 1
  for (int t = 0; t < 30; t += 2) {
    stage(t + 1, 1);
    asm volatile("s_waitcnt vmcnt(6)" ::: "memory");  // tile t landed
    __builtin_amdgcn_s_barrier();
    compute(0);
    __builtin_amdgcn_s_barrier();
    stage(t + 2, 0);
    asm volatile("s_waitcnt vmcnt(6)" ::: "memory");  // tile t+1 landed
    __builtin_amdgcn_s_barrier();
    compute(1);
    __builtin_amdgcn_s_barrier();
  }
  // t=30
  stage(31, 1);
  asm volatile("s_waitcnt vmcnt(6)" ::: "memory");
  __builtin_amdgcn_s_barrier();
  compute(0);
  __builtin_amdgcn_s_barrier();
  // t=31
  asm volatile("s_waitcnt vmcnt(0)" ::: "memory");
  __builtin_amdgcn_s_barrier();
  compute(1);

  // epilogue: row = m0 + wm*64 + mt*16 + quad*4 + r;
  //           col = n0 + wn*64 + nt*16 + l15   (verified map)
#pragma unroll
  for (int mt = 0; mt < 4; mt++)
#pragma unroll
    for (int nt = 0; nt < 4; nt++) {
      const int colg = n0 + wn * 64 + nt * 16 + l15;
      const int row0 = m0 + wm * 64 + mt * 16 + quad * 4;
      if (FUSEV && (colg >> 11) == 2) {
        // V: write directly transposed (B,H,Dh,L). rows are consecutive l.
        const int hd = colg & 2047;  // h*128 + d
        const int bb = row0 >> 11, ll = row0 & 2047;
        const size_t off =
            (((size_t)(bb * 16 + (hd >> 7))) * 128 + (hd & 127)) * 2048 + ll;
#pragma unroll
        for (int r = 0; r < 4; r++) Vt[off + r] = f2b(acc[mt][nt][r]);
      } else {
        const size_t cbase =
            (size_t)(colg >> 11) * bufStride + (colg & 2047);
#pragma unroll
        for (int r = 0; r < 4; r++) {
          const float v = acc[mt][nt][r];
          if constexpr (sizeof(OutT) == 2)
            C[cbase + (size_t)(row0 + r) * 2048] = f2b(v);
          else
            C[cbase + (size_t)(row0 + r) * 2048] = v;
        }
      }
    }
}

__global__ __launch_bounds__(512, 1) void gemmk_bf(const u16* __restrict__ A,
                                                   const u16* __restrict__ Bt,
                                                   u16* __restrict__ C,
                                                   u16* __restrict__ Vt,
                                                   int nwg, size_t bufStride) {
  gemmk_core<u16, true>(A, Bt, C, Vt, nwg, bufStride);
}
__global__ __launch_bounds__(512, 1) void gemmk_f32(const u16* __restrict__ A,
                                                    const u16* __restrict__ Bt,
                                                    float* __restrict__ C,
                                                    int nwg, size_t bufStride) {
  gemmk_core<float, false>(A, Bt, C, nullptr, nwg, bufStride);
}

// ---------------------------------------------------------------------------
// RoPE in place on Q and K; Q additionally scaled by 1/sqrt(Dh).
// One thread per (l,h,j), batch loop inside; exp2f (native v_exp_f32).
// ---------------------------------------------------------------------------
__global__ __launch_bounds__(256) void rope_qk(u16* __restrict__ Q, u16* __restrict__ K) {
  const int idx = blockIdx.x * 256 + threadIdx.x;  // (l, h, j)
  const int j = idx & 63;
  const int h = (idx >> 6) & 15;
  const int l = idx >> 10;
  const float inv = exp2f(-0.2958057561f * (float)j);  // theta^(-j/64)
  const float ang = (float)l * inv;
  float s, c;
  sincosf(ang, &s, &c);
  const float sc = 0.08838834764f;  // 1/sqrt(128)
#pragma unroll
  for (int b = 0; b < Bb; b++) {
    const size_t off = ((size_t)((b * Lc + l) * Hc + h)) * DhC + 2 * j;
    const float q0 = b2f(Q[off]), q1 = b2f(Q[off + 1]);
    const float k0 = b2f(K[off]), k1 = b2f(K[off + 1]);
    Q[off]     = f2b((q0 * c - q1 * s) * sc);
    Q[off + 1] = f2b((q1 * c + q0 * s) * sc);
    K[off]     = f2b(k0 * c - k1 * s);
    K[off + 1] = f2b(k1 * c + k0 * s);
  }
}

// ---------------------------------------------------------------------------
// Flash attention (causal), unchanged from passing round-1 version.
// ---------------------------------------------------------------------------
#define NEGBIG (-3.0e30f)
__global__ __launch_bounds__(256, 2) void flash_attn(const u16* __restrict__ Q,
                                                     const u16* __restrict__ Kg,
                                                     const u16* __restrict__ Vt,
                                                     u16* __restrict__ O) {
  __shared__ __align__(16) u16 Ks[2][64 * 128];
  __shared__ __align__(16) u16 Vs[2][128 * 64];
  const int tid = threadIdx.x;
  const int lane = tid & 63, w = tid >> 6;
  const int l31 = lane & 31, hib = lane >> 5;
  const int bh = blockIdx.y;
  const int b = bh >> 4, h = bh & 15;
  const int qt = (bh & 16) ? (int)blockIdx.x : (15 - (int)blockIdx.x);
  const int q0 = qt * 128;
  const int qw0 = q0 + w * 32;
  const int nkv = 2 * qt + 2;

  const int krl = lane >> 4, ksl = lane & 15;
  const int vrl = lane >> 3, vsl = lane & 7;

  bf16x8 qf[8];
  {
    const u16* qptr = Q + ((size_t)(b * Lc + qw0 + l31) * Hc + h) * DhC + 8 * hib;
#pragma unroll
    for (int s = 0; s < 8; s++) qf[s] = *(const bf16x8*)(qptr + s * 16);
  }

  {
#pragma unroll
    for (int p = 0; p < 4; p++) {
      const int r = p * 16 + w * 4 + krl;
      const int c = ksl ^ (r & 15);
      gll16(Kg + ((size_t)(b * Lc + r) * Hc + h) * DhC + c * 8,
            &Ks[0][(p * 256 + w * 64) * 8]);
    }
#pragma unroll
    for (int p = 0; p < 4; p++) {
      const int r = p * 32 + w * 8 + vrl;
      const int c = vsl ^ (r & 7);
      gll16(Vt + ((size_t)bh * DhC + r) * Lc + c * 8,
            &Vs[0][(p * 256 + w * 64) * 8]);
    }
  }

  f32x16 o[4];
#pragma unroll
  for (int dt = 0; dt < 4; dt++) o[dt] = (f32x16)0.0f;
  float mrow = NEGBIG, lrow = 0.f;

  __syncthreads();

  for (int kvt = 0; kvt < nkv; kvt++) {
    const int cur = kvt & 1;
    const u16* Ksc = Ks[cur];
    const u16* Vsc = Vs[cur];

    if (kvt + 1 < nkv) {
      const int nv0 = (kvt + 1) * 64;
      const int nxt = cur ^ 1;
#pragma unroll
      for (int p = 0; p < 4; p++) {
        const int r = p * 16 + w * 4 + krl;
        const int c = ksl ^ (r & 15);
        gll16(Kg + ((size_t)(b * Lc + nv0 + r) * Hc + h) * DhC + c * 8,
              &Ks[nxt][(p * 256 + w * 64) * 8]);
      }
#pragma unroll
      for (int p = 0; p < 4; p++) {
        const int r = p * 32 + w * 8 + vrl;
        const int c = vsl ^ (r & 7);
        gll16(Vt + ((size_t)bh * DhC + r) * Lc + nv0 + c * 8,
              &Vs[nxt][(p * 256 + w * 64) * 8]);
      }
    }

    const int kv0 = kvt * 64;
    const bool active = (kv0 <= qw0 + 31);
    if (active) {
      f32x16 s0 = (f32x16)0.0f, s1 = (f32x16)0.0f;
      __builtin_amdgcn_s_setprio(1);
#pragma unroll
      for (int s = 0; s < 8; s++) {
        const int ch = ((2 * s + hib) ^ (l31 & 15)) * 8;
        bf16x8 k0 = *(const bf16x8*)(&Ksc[l31 * 128 + ch]);
        bf16x8 k1 = *(const bf16x8*)(&Ksc[(32 + l31) * 128 + ch]);
        s0 = __builtin_amdgcn_mfma_f32_32x32x16_bf16(k0, qf[s], s0, 0, 0, 0);
        s1 = __builtin_amdgcn_mfma_f32_32x32x16_bf16(k1, qf[s], s1, 0, 0, 0);
      }
      __builtin_amdgcn_s_setprio(0);

      if (kv0 + 63 > qw0) {
        const int qg = qw0 + l31;
#pragma unroll
        for (int r = 0; r < 16; r++) {
          const int cr = (r & 3) + 8 * (r >> 2) + 4 * hib;
          if (kv0 + cr > qg) s0[r] = NEGBIG;
          if (kv0 + 32 + cr > qg) s1[r] = NEGBIG;
        }
      }

      float mx;
      {
        float a[8];
#pragma unroll
        for (int i = 0; i < 8; i++)
          a[i] = fmaxf(fmaxf(s0[i], s0[i + 8]), fmaxf(s1[i], s1[i + 8]));
        float b0 = fmaxf(a[0], a[4]), b1 = fmaxf(a[1], a[5]);
        float b2 = fmaxf(a[2], a[6]), b3 = fmaxf(a[3], a[7]);
        mx = fmaxf(fmaxf(b0, b1), fmaxf(b2, b3));
      }
      mx = fmaxf(mx, __shfl_xor(mx, 32, 64));

      if (!__all(mx - mrow <= 8.f)) {
        const float mnew = fmaxf(mrow, mx);
        const float al = __expf(mrow - mnew);
#pragma unroll
        for (int dt = 0; dt < 4; dt++)
#pragma unroll
          for (int e = 0; e < 16; e++) o[dt][e] *= al;
        lrow *= al;
        mrow = mnew;
      }

#pragma unroll
      for (int i = 0; i < 16; i++) {
        s0[i] = __expf(s0[i] - mrow);
        s1[i] = __expf(s1[i] - mrow);
      }
      float sm;
      {
        float a[8];
#pragma unroll
        for (int i = 0; i < 8; i++)
          a[i] = (s0[i] + s0[i + 8]) + (s1[i] + s1[i + 8]);
        sm = ((a[0] + a[4]) + (a[1] + a[5])) + ((a[2] + a[6]) + (a[3] + a[7]));
      }
      sm += __shfl_xor(sm, 32, 64);
      lrow += sm;

      bf16x8 paf[4];
#pragma unroll
      for (int t = 0; t < 2; t++) {
#pragma unroll
        for (int h8 = 0; h8 < 2; h8++) {
          const int rB = 8 * h8;
          u32 lo0, lo1, hi0, hi1;
          if (t == 0) {
            lo0 = cvtpk(s0[rB + 0], s0[rB + 1]);
            lo1 = cvtpk(s0[rB + 2], s0[rB + 3]);
            hi0 = cvtpk(s0[rB + 4], s0[rB + 5]);
            hi1 = cvtpk(s0[rB + 6], s0[rB + 7]);
          } else {
            lo0 = cvtpk(s1[rB + 0], s1[rB + 1]);
            lo1 = cvtpk(s1[rB + 2], s1[rB + 3]);
            hi0 = cvtpk(s1[rB + 4], s1[rB + 5]);
            hi1 = cvtpk(s1[rB + 6], s1[rB + 7]);
          }
          const u32 g0 = hib ? lo0 : hi0;
          const u32 g1 = hib ? lo1 : hi1;
          const u32 r0 = (u32)__shfl_xor((int)g0, 32, 64);
          const u32 r1 = (u32)__shfl_xor((int)g1, 32, 64);
          union { u32 u[4]; bf16x8 v; } pu;
          pu.u[0] = hib ? r0 : lo0;
          pu.u[1] = hib ? r1 : lo1;
          pu.u[2] = hib ? hi0 : r0;
          pu.u[3] = hib ? hi1 : r1;
          paf[2 * t + h8] = pu.v;
        }
      }

      __builtin_amdgcn_s_setprio(1);
#pragma unroll
      for (int B = 0; B < 4; B++) {
#pragma unroll
        for (int dt = 0; dt < 4; dt++) {
          const bf16x8 vf = *(const bf16x8*)(
              &Vsc[(32 * dt + l31) * 64 + (((2 * B + hib) ^ (l31 & 7))) * 8]);
          o[dt] = __builtin_amdgcn_mfma_f32_32x32x16_bf16(paf[B], vf, o[dt], 0, 0, 0);
        }
      }
      __builtin_amdgcn_s_setprio(0);
    }

    __syncthreads();
  }

#pragma unroll
  for (int r = 0; r < 16; r++) {
    const int cr = (r & 3) + 8 * (r >> 2) + 4 * hib;
    const float linv = 1.0f / __shfl(lrow, cr, 64);
    const size_t rowoff = ((size_t)(b * Lc + qw0 + cr) * Hc + h) * DhC + l31;
#pragma unroll
    for (int dt = 0; dt < 4; dt++)
      O[rowoff + 32 * dt] = f2b(o[dt][r] * linv);
  }
}

// ---------------------------------------------------------------------------
// ws layout (72 MiB + 256 B peak):
//   [0,256) flag | WT 8MiB (Wo only) | xc 16MiB | Qb 16MiB | Kb 16MiB | Vt 16MiB
//   QKV gemm: reads xc + WTall(d_out); writes Qb, Kb (via col>>11) and V
//   DIRECTLY TRANSPOSED into Vt. Ob = xc (dead after QKV gemm). WTall dead
//   after QKV gemm; final gemm overwrites d_out.
// ---------------------------------------------------------------------------
extern "C" void kernel_launch(void* const* d_in, const int* in_sizes, int n_in,
                              void* d_out, int out_size, void* d_ws, size_t ws_size,
                              hipStream_t stream) {
  const void* x  = d_in[0];
  const void* Wq = d_in[1];
  const void* Wk = d_in[2];
  const void* Wv = d_in[3];
  const void* Wo = d_in[4];
  float* out = (float*)d_out;   // reference output dtype: float32 (verified r4)

  char* w = (char*)d_ws;
  const size_t WSZ = (size_t)2048 * 2048;
  const size_t XSZ = (size_t)Bb * Lc * Dc;
  int* flag = (int*)w;
  u16* WT  = (u16*)(w + 256);
  u16* xc  = WT + WSZ;
  u16* Qb  = xc + XSZ;
  u16* Kb  = Qb + XSZ;
  u16* Vtb = Kb + XSZ;   // V written directly transposed here
  u16* Ob  = xc;          // xc dead after QKV gemm
  u16* WTall = (u16*)d_out;   // 24 MiB scratch inside the 32 MiB output

  sniff_dtype<<<1, 256, 0, stream>>>((const u16*)x, flag);
  conv_x<<<(int)(XSZ / 1024), 256, 0, stream>>>(x, xc, flag);

  // all three QKV weight transposes in one dispatch
  transpose3_conv<<<dim3(32, 32, 3), 256, 0, stream>>>(Wq, Wk, Wv, WTall, flag);

  // fused QKV: C[4096, 6144] = xc @ [Wq|Wk|Wv]^T -> Qb/Kb via col>>11,
  // V directly transposed into Vtb
  gemmk_bf<<<dim3(768), 512, 0, stream>>>(xc, WTall, Qb, Vtb, 768, XSZ);

  rope_qk<<<(Lc * Hc * 64) / 256, 256, 0, stream>>>(Qb, Kb);

  dim3 fgrid(16, 32);
  flash_attn<<<fgrid, 256, 0, stream>>>(Qb, Kb, Vtb, Ob);

  dim3 tgrid(32, 32);
  transpose2d_conv<<<tgrid, 256, 0, stream>>>(Wo, WT, flag);
  gemmk_f32<<<dim3(256), 512, 0, stream>>>(Ob, WT, out, 256, 0);
}